// Round 5
// baseline (292.067 us; speedup 1.0000x reference)
//
#include <hip/hip_runtime.h>

#define B_    16
#define N_    65536
#define C_    256
#define DIN_  16
#define DOUT_ 16

typedef float f32x4 __attribute__((ext_vector_type(4)));

// workspace layout (floats):
//   s      [DIN_][B_][C_]    = 65536 floats  (s[i][b][k])
//   off    [B_][C_][DOUT_]   = 65536 floats  (includes /N and +b1)
//   wd_t   [C_][DIN_*DOUT_]  = 65536 floats  (wd_t[c][i*16+o])
//   c_of_n [N_]              = 65536 ints    (cluster id of source row n)

// ---------------------------------------------------------------------------
// K0 (k_pre): zero s (scatter target) + build c_of_n.  320 blocks.
// ---------------------------------------------------------------------------
__global__ __launch_bounds__(256) void k_pre(
    const int* __restrict__ P, float* __restrict__ s, int* __restrict__ c_of_n)
{
    int bid = blockIdx.x;
    int t = threadIdx.x;
    if (bid < 64) {
        reinterpret_cast<float4*>(s)[bid * 256 + t] =
            make_float4(0.f, 0.f, 0.f, 0.f);
    } else {
        int k = bid - 64;                       // 0..255
        c_of_n[P[k * 256 + t]] = k;
    }
}

// ---------------------------------------------------------------------------
// K1 (k_scat): cluster sums by SCATTER (coalesced x stream, LDS accumulate).
//   blocks [0,512): (b = bid>>5, chunk = bid&31) — 2048 rows, 128 KB x, all
//     float4-coalesced. LDS table s_loc[256][17] (pad 17: conflict-free both
//     in atomic phase and flush). Flush: coalesced global atomicAdd.
//   blocks [512,768): transpose w_diag -> wd_t (as before).
// ---------------------------------------------------------------------------
__global__ __launch_bounds__(256) void k_scat(
    const float* __restrict__ x, const float* __restrict__ w_diag,
    const int* __restrict__ c_of_n, float* __restrict__ s,
    float* __restrict__ wd_t)
{
    int bid = blockIdx.x;
    int t = threadIdx.x;
    if (bid >= 512) {
        int r = bid - 512;
        int o = r >> 4, i = r & 15;
        wd_t[t * 256 + i * 16 + o] = w_diag[r * C_ + t];  // coalesced read
        return;
    }
    __shared__ float s_loc[256 * 17];
    #pragma unroll
    for (int r = t; r < 256 * 17; r += 256) s_loc[r] = 0.f;
    __syncthreads();

    int b    = bid >> 5;          // 0..15
    int ch   = bid & 31;          // 0..31
    int n0   = ch * 2048;
    int quad = t & 3;             // which float4 of the row
    int rsub = t >> 2;            // 0..63 rows per block-iteration

    const float4* x4 = reinterpret_cast<const float4*>(x);
    const size_t base = ((size_t)b * N_ + n0) * 4;   // float4 units

    for (int it = 0; it < 32; ++it) {
        int nl = it * 64 + rsub;
        int k  = c_of_n[n0 + nl];
        float4 v = x4[base + (size_t)nl * 4 + quad];  // fully coalesced
        float* dst = &s_loc[k * 17 + quad * 4];
        atomicAdd(dst + 0, v.x);
        atomicAdd(dst + 1, v.y);
        atomicAdd(dst + 2, v.z);
        atomicAdd(dst + 3, v.w);
    }
    __syncthreads();
    // flush: thread t owns k=t; global addresses coalesced per i
    #pragma unroll
    for (int i = 0; i < 16; ++i)
        atomicAdd(&s[i * 4096 + b * 256 + t], s_loc[t * 17 + i]);
}

// ---------------------------------------------------------------------------
// K2: off[b,c,o] = invN * sum_{i,k} w_off[o,i,c,k]*s[i,b,k] + b1[o]
// grid = C_*4 = 1024 blocks: (c = bid>>2, o-quad o0 = (bid&3)*4).
//   o-split (not b-split) => NO duplicated w traffic (67 MB logical total).
//   512 threads = 8 waves; wave w owns b-pair b0 = 2w; lane kq owns k-quad.
//   acc[o4*2+bq] = 8 regs. Counted-vmcnt pipeline (raw s_barrier + lgkmcnt
//   only; prefetches stay in flight across barriers). ~24 waves/CU.
// ---------------------------------------------------------------------------
__global__ __launch_bounds__(512, 6) void k_off(
    const float* __restrict__ w_off, const float* __restrict__ s,
    const float* __restrict__ b1, float* __restrict__ off)
{
    const int c  = (int)blockIdx.x >> 2;
    const int o0 = ((int)blockIdx.x & 3) * 4;
    const int t  = threadIdx.x;       // 0..511
    const int kq = t & 63;
    const int w  = t >> 6;            // 0..7
    const int b0 = w * 2;

    __shared__ float4 slds[2][1024];  // [buf][b*64 + kq], 16 KB per buf

    const float4* s4 = reinterpret_cast<const float4*>(s);
    const float4* w4 = reinterpret_cast<const float4*>(w_off);

    // float4 index of w_off[o][i][c][kq*4] = o*262144 + i*16384 + c*64 + kq
    int wbase[4];
    #pragma unroll
    for (int o4 = 0; o4 < 4; ++o4)
        wbase[o4] = (o0 + o4) * 262144 + c * 64 + kq;

    float acc[8];    // acc[o4*2 + bq]
    #pragma unroll
    for (int z = 0; z < 8; ++z) acc[z] = 0.f;

    float4 wA[4], wB[4], sA[2], sB[2];

    // prologue: slice0 -> LDS buf0; w(0) -> wA; slice1 -> sA
    {
        float4 p0 = s4[t], p1 = s4[t + 512];
        #pragma unroll
        for (int o4 = 0; o4 < 4; ++o4) wA[o4] = w4[wbase[o4]];
        sA[0] = s4[1024 + t];
        sA[1] = s4[1024 + t + 512];
        slds[0][t] = p0;
        slds[0][t + 512] = p1;
        asm volatile("s_waitcnt lgkmcnt(0)" ::: "memory");
        __builtin_amdgcn_s_barrier();
    }

#define K2_BODY(I, WC, WN, SR, SI, RB)                                         \
    {                                                                          \
        if ((I) + 2 < DIN_) {                                                  \
            SI[0] = s4[((I) + 2) * 1024 + t];                                  \
            SI[1] = s4[((I) + 2) * 1024 + t + 512];                            \
        }                                                                      \
        if ((I) + 1 < DIN_) {                                                  \
            _Pragma("unroll")                                                  \
            for (int o4 = 0; o4 < 4; ++o4)                                     \
                WN[o4] = w4[wbase[o4] + ((I) + 1) * 16384];                    \
        }                                                                      \
        _Pragma("unroll")                                                      \
        for (int bq = 0; bq < 2; ++bq) {                                       \
            float4 sv = slds[RB][(b0 + bq) * 64 + kq];                         \
            _Pragma("unroll")                                                  \
            for (int o4 = 0; o4 < 4; ++o4)                                     \
                acc[o4 * 2 + bq] += WC[o4].x * sv.x + WC[o4].y * sv.y          \
                                  + WC[o4].z * sv.z + WC[o4].w * sv.w;         \
        }                                                                      \
        if ((I) + 1 < DIN_) {                                                  \
            slds[(RB) ^ 1][t]       = SR[0];                                   \
            slds[(RB) ^ 1][t + 512] = SR[1];                                   \
            asm volatile("s_waitcnt lgkmcnt(0)" ::: "memory");                 \
            __builtin_amdgcn_s_barrier();                                      \
        }                                                                      \
    }

    #pragma unroll
    for (int ih = 0; ih < DIN_ / 2; ++ih) {
        K2_BODY(2 * ih,     wA, wB, sA, sB, 0)
        K2_BODY(2 * ih + 1, wB, wA, sB, sA, 1)
    }
#undef K2_BODY

    // fold-halving reduce: 8 values x 64 lanes. 3 folds + 3 plain xor-adds.
    // Lane l<8 ends with the full k-sum of value j = bitrev3(l).
#define FOLD(MASK, CNT)                                                        \
    {                                                                          \
        const bool hi_ = (kq & (MASK)) != 0;                                   \
        _Pragma("unroll")                                                      \
        for (int j = 0; j < (CNT); ++j) {                                      \
            float keep = hi_ ? acc[j + (CNT)] : acc[j];                        \
            float send = hi_ ? acc[j] : acc[j + (CNT)];                        \
            acc[j] = keep + __shfl_xor(send, (MASK), 64);                      \
        }                                                                      \
    }
    FOLD(1, 4) FOLD(2, 2) FOLD(4, 1)
#undef FOLD
    acc[0] += __shfl_xor(acc[0], 8, 64);
    acc[0] += __shfl_xor(acc[0], 16, 64);
    acc[0] += __shfl_xor(acc[0], 32, 64);

    if (kq < 8) {
        int j  = ((kq & 1) << 2) | (kq & 2) | ((kq & 4) >> 2);  // bitrev3
        int bq = j & 1;
        int o4 = j >> 1;
        int b  = b0 + bq;
        int o  = o0 + o4;
        off[((b << 8) + c) * DOUT_ + o] = acc[0] * (1.0f / (float)N_) + b1[o];
    }
}

// ---------------------------------------------------------------------------
// K3: sequential apply. Non-temporal out stores: out (67 MB, never re-read)
// must not evict x / w_off from L3 (working set then ~168 MB < 256 MB L3).
// nontemporal builtin needs a native clang vector type, not HIP float4.
// ---------------------------------------------------------------------------
__global__ __launch_bounds__(256) void k_apply_seq(
    const float* __restrict__ x, const int* __restrict__ c_of_n,
    const float* __restrict__ wd_t, const float* __restrict__ off,
    float* __restrict__ out)
{
    int t = threadIdx.x;
    int lr = t >> 2, q = t & 3;
    int n = blockIdx.x * 64 + lr;
    int c = c_of_n[n];

    const float4* wd4 = reinterpret_cast<const float4*>(wd_t);
    float4 wds[16];
    #pragma unroll
    for (int i = 0; i < 16; ++i) wds[i] = wd4[c * 64 + i * 4 + q];

    const float4* x4   = reinterpret_cast<const float4*>(x);
    const float4* off4 = reinterpret_cast<const float4*>(off);
    f32x4* out4        = reinterpret_cast<f32x4*>(out);

    #pragma unroll 2
    for (int b = 0; b < B_; ++b) {
        size_t rowbase = ((size_t)(b * N_ + n)) * 4;
        float4 x0 = x4[rowbase + 0];
        float4 x1 = x4[rowbase + 1];
        float4 x2 = x4[rowbase + 2];
        float4 x3 = x4[rowbase + 3];
        float4 acc = off4[((size_t)((b << 8) + c)) * 4 + q];
        float xv[16];
        xv[0]=x0.x; xv[1]=x0.y; xv[2]=x0.z; xv[3]=x0.w;
        xv[4]=x1.x; xv[5]=x1.y; xv[6]=x1.z; xv[7]=x1.w;
        xv[8]=x2.x; xv[9]=x2.y; xv[10]=x2.z; xv[11]=x2.w;
        xv[12]=x3.x; xv[13]=x3.y; xv[14]=x3.z; xv[15]=x3.w;
        #pragma unroll
        for (int i = 0; i < 16; ++i) {
            acc.x += xv[i] * wds[i].x;
            acc.y += xv[i] * wds[i].y;
            acc.z += xv[i] * wds[i].z;
            acc.w += xv[i] * wds[i].w;
        }
        f32x4 accv;
        accv.x = acc.x; accv.y = acc.y; accv.z = acc.z; accv.w = acc.w;
        __builtin_nontemporal_store(accv, &out4[rowbase + q]);
    }
}

extern "C" void kernel_launch(void* const* d_in, const int* in_sizes, int n_in,
                              void* d_out, int out_size, void* d_ws, size_t ws_size,
                              hipStream_t stream) {
    const float* x      = (const float*)d_in[0];
    const float* w_diag = (const float*)d_in[1];
    const float* w_off  = (const float*)d_in[2];
    const float* b1     = (const float*)d_in[3];
    const int*   P      = (const int*)d_in[4];
    float* out    = (float*)d_out;
    float* s      = (float*)d_ws;          // 65536 floats
    float* off    = s + 65536;             // 65536 floats
    float* wd_t   = off + 65536;           // 65536 floats
    int*   c_of_n = (int*)(wd_t + 65536);  // 65536 ints

    k_pre<<<320, 256, 0, stream>>>(P, s, c_of_n);
    k_scat<<<768, 256, 0, stream>>>(x, w_diag, c_of_n, s, wd_t);
    k_off<<<C_ * 4, 512, 0, stream>>>(w_off, s, b1, off);
    k_apply_seq<<<N_ / 64, 256, 0, stream>>>(x, c_of_n, wd_t, off, out);
}

// Round 6
// 220.724 us; speedup vs baseline: 1.3232x; 1.3232x over previous
//
#include <hip/hip_runtime.h>

#define B_    16
#define N_    65536
#define C_    256
#define DIN_  16
#define DOUT_ 16

typedef float f32x4 __attribute__((ext_vector_type(4)));

// workspace layout (floats):
//   s      [DIN_][B_][C_]    = 65536 floats  (s[i][b][k])
//   off    [B_][C_][DOUT_]   = 65536 floats  (includes /N and +b1)
//   wd_t   [C_][DIN_*DOUT_]  = 65536 floats  (wd_t[c][i*16+o])
//   c_of_n [N_]              = 65536 ints    (cluster id of source row n)

// ---------------------------------------------------------------------------
// K1: fused prep + cluster sums (gather form — R0-proven, ~34 µs).
//   blocks [0, 4096): gather-style cluster sum for (b, k) — no atomics.
//   blocks [4096, 4352): transpose w_diag[o][i][c] -> wd_t[c][i*16+o]
//   blocks [4352, 4608): c_of_n[P[j]] = j>>8
// ---------------------------------------------------------------------------
__global__ __launch_bounds__(256) void k_sum_prep(
    const float* __restrict__ x, const float* __restrict__ w_diag,
    const int* __restrict__ P, float* __restrict__ s,
    float* __restrict__ wd_t, int* __restrict__ c_of_n)
{
    int bid = blockIdx.x;
    int t = threadIdx.x;
    if (bid >= B_ * C_) {
        int r = bid - B_ * C_;
        if (r < 256) {
            int o = r >> 4, i = r & 15;
            wd_t[t * 256 + i * 16 + o] = w_diag[r * C_ + t];  // coalesced read
        } else {
            int k = r - 256;
            c_of_n[P[k * 256 + t]] = k;
        }
        return;
    }
    int b = bid >> 8;
    int k = bid & (C_ - 1);
    int q  = t & 3;         // which float4 of the 16-float row
    int rg = t >> 2;        // 0..63 row group
    float4 acc = make_float4(0.f, 0.f, 0.f, 0.f);
    const int jbase = k << 8;
    #pragma unroll
    for (int m = 0; m < 4; ++m) {
        int n = P[jbase + rg + 64 * m];
        const float4* row =
            reinterpret_cast<const float4*>(x + ((size_t)(b * N_ + n)) * DIN_);
        float4 v = row[q];
        acc.x += v.x; acc.y += v.y; acc.z += v.z; acc.w += v.w;
    }
    // butterfly reduce over row-groups within the wave (bits 2..5 of lane id)
    #pragma unroll
    for (int mask = 4; mask <= 32; mask <<= 1) {
        acc.x += __shfl_xor(acc.x, mask, 64);
        acc.y += __shfl_xor(acc.y, mask, 64);
        acc.z += __shfl_xor(acc.z, mask, 64);
        acc.w += __shfl_xor(acc.w, mask, 64);
    }
    __shared__ float4 part[4][4];  // [wave][q]
    int lane = t & 63, wave = t >> 6;
    if (lane < 4) part[wave][lane] = acc;  // lane == q for lanes 0..3
    __syncthreads();
    if (t < 16) {
        int qq = t >> 2, comp = t & 3;
        float v = 0.f;
        #pragma unroll
        for (int w = 0; w < 4; ++w) {
            const float* p = reinterpret_cast<const float*>(&part[w][qq]);
            v += p[comp];
        }
        int i = qq * 4 + comp;
        s[i * (B_ * C_) + b * C_ + k] = v;
    }
}

// ---------------------------------------------------------------------------
// K2: off[b,c,o] = invN * sum_{i,k} w_off[o,i,c,k]*s[i,b,k] + b1[o]
// grid = C_*4 = 1024 blocks: (c = bid>>2, o-quad o0 = (bid&3)*4).
//   o-split (not b-split) => NO duplicated w traffic (67 MB logical total).
//   512 threads = 8 waves; wave w owns b-pair b0 = 2w; lane kq owns k-quad.
//   acc[o4*2+bq] = 8 regs. Counted-vmcnt pipeline (raw s_barrier + lgkmcnt
//   only; prefetches stay in flight across barriers). ~24 waves/CU.
// ---------------------------------------------------------------------------
__global__ __launch_bounds__(512, 6) void k_off(
    const float* __restrict__ w_off, const float* __restrict__ s,
    const float* __restrict__ b1, float* __restrict__ off)
{
    const int c  = (int)blockIdx.x >> 2;
    const int o0 = ((int)blockIdx.x & 3) * 4;
    const int t  = threadIdx.x;       // 0..511
    const int kq = t & 63;
    const int w  = t >> 6;            // 0..7
    const int b0 = w * 2;

    __shared__ float4 slds[2][1024];  // [buf][b*64 + kq], 16 KB per buf

    const float4* s4 = reinterpret_cast<const float4*>(s);
    const float4* w4 = reinterpret_cast<const float4*>(w_off);

    // float4 index of w_off[o][i][c][kq*4] = o*262144 + i*16384 + c*64 + kq
    int wbase[4];
    #pragma unroll
    for (int o4 = 0; o4 < 4; ++o4)
        wbase[o4] = (o0 + o4) * 262144 + c * 64 + kq;

    float acc[8];    // acc[o4*2 + bq]
    #pragma unroll
    for (int z = 0; z < 8; ++z) acc[z] = 0.f;

    float4 wA[4], wB[4], sA[2], sB[2];

    // prologue: slice0 -> LDS buf0; w(0) -> wA; slice1 -> sA
    {
        float4 p0 = s4[t], p1 = s4[t + 512];
        #pragma unroll
        for (int o4 = 0; o4 < 4; ++o4) wA[o4] = w4[wbase[o4]];
        sA[0] = s4[1024 + t];
        sA[1] = s4[1024 + t + 512];
        slds[0][t] = p0;
        slds[0][t + 512] = p1;
        asm volatile("s_waitcnt lgkmcnt(0)" ::: "memory");
        __builtin_amdgcn_s_barrier();
    }

#define K2_BODY(I, WC, WN, SR, SI, RB)                                         \
    {                                                                          \
        if ((I) + 2 < DIN_) {                                                  \
            SI[0] = s4[((I) + 2) * 1024 + t];                                  \
            SI[1] = s4[((I) + 2) * 1024 + t + 512];                            \
        }                                                                      \
        if ((I) + 1 < DIN_) {                                                  \
            _Pragma("unroll")                                                  \
            for (int o4 = 0; o4 < 4; ++o4)                                     \
                WN[o4] = w4[wbase[o4] + ((I) + 1) * 16384];                    \
        }                                                                      \
        _Pragma("unroll")                                                      \
        for (int bq = 0; bq < 2; ++bq) {                                       \
            float4 sv = slds[RB][(b0 + bq) * 64 + kq];                         \
            _Pragma("unroll")                                                  \
            for (int o4 = 0; o4 < 4; ++o4)                                     \
                acc[o4 * 2 + bq] += WC[o4].x * sv.x + WC[o4].y * sv.y          \
                                  + WC[o4].z * sv.z + WC[o4].w * sv.w;         \
        }                                                                      \
        if ((I) + 1 < DIN_) {                                                  \
            slds[(RB) ^ 1][t]       = SR[0];                                   \
            slds[(RB) ^ 1][t + 512] = SR[1];                                   \
            asm volatile("s_waitcnt lgkmcnt(0)" ::: "memory");                 \
            __builtin_amdgcn_s_barrier();                                      \
        }                                                                      \
    }

    #pragma unroll
    for (int ih = 0; ih < DIN_ / 2; ++ih) {
        K2_BODY(2 * ih,     wA, wB, sA, sB, 0)
        K2_BODY(2 * ih + 1, wB, wA, sB, sA, 1)
    }
#undef K2_BODY

    // fold-halving reduce: 8 values x 64 lanes. 3 folds + 3 plain xor-adds.
    // Lane l<8 ends with the full k-sum of value j = bitrev3(l).
#define FOLD(MASK, CNT)                                                        \
    {                                                                          \
        const bool hi_ = (kq & (MASK)) != 0;                                   \
        _Pragma("unroll")                                                      \
        for (int j = 0; j < (CNT); ++j) {                                      \
            float keep = hi_ ? acc[j + (CNT)] : acc[j];                        \
            float send = hi_ ? acc[j] : acc[j + (CNT)];                        \
            acc[j] = keep + __shfl_xor(send, (MASK), 64);                      \
        }                                                                      \
    }
    FOLD(1, 4) FOLD(2, 2) FOLD(4, 1)
#undef FOLD
    acc[0] += __shfl_xor(acc[0], 8, 64);
    acc[0] += __shfl_xor(acc[0], 16, 64);
    acc[0] += __shfl_xor(acc[0], 32, 64);

    if (kq < 8) {
        int j  = ((kq & 1) << 2) | (kq & 2) | ((kq & 4) >> 2);  // bitrev3
        int bq = j & 1;
        int o4 = j >> 1;
        int b  = b0 + bq;
        int o  = o0 + o4;
        off[((b << 8) + c) * DOUT_ + o] = acc[0] * (1.0f / (float)N_) + b1[o];
    }
}

// ---------------------------------------------------------------------------
// K3: sequential apply. Non-temporal out stores: out (67 MB, never re-read)
// must not evict x / w_off from L3 (working set then ~168 MB < 256 MB L3).
// nontemporal builtin needs a native clang vector type, not HIP float4.
// ---------------------------------------------------------------------------
__global__ __launch_bounds__(256) void k_apply_seq(
    const float* __restrict__ x, const int* __restrict__ c_of_n,
    const float* __restrict__ wd_t, const float* __restrict__ off,
    float* __restrict__ out)
{
    int t = threadIdx.x;
    int lr = t >> 2, q = t & 3;
    int n = blockIdx.x * 64 + lr;
    int c = c_of_n[n];

    const float4* wd4 = reinterpret_cast<const float4*>(wd_t);
    float4 wds[16];
    #pragma unroll
    for (int i = 0; i < 16; ++i) wds[i] = wd4[c * 64 + i * 4 + q];

    const float4* x4   = reinterpret_cast<const float4*>(x);
    const float4* off4 = reinterpret_cast<const float4*>(off);
    f32x4* out4        = reinterpret_cast<f32x4*>(out);

    #pragma unroll 2
    for (int b = 0; b < B_; ++b) {
        size_t rowbase = ((size_t)(b * N_ + n)) * 4;
        float4 x0 = x4[rowbase + 0];
        float4 x1 = x4[rowbase + 1];
        float4 x2 = x4[rowbase + 2];
        float4 x3 = x4[rowbase + 3];
        float4 acc = off4[((size_t)((b << 8) + c)) * 4 + q];
        float xv[16];
        xv[0]=x0.x; xv[1]=x0.y; xv[2]=x0.z; xv[3]=x0.w;
        xv[4]=x1.x; xv[5]=x1.y; xv[6]=x1.z; xv[7]=x1.w;
        xv[8]=x2.x; xv[9]=x2.y; xv[10]=x2.z; xv[11]=x2.w;
        xv[12]=x3.x; xv[13]=x3.y; xv[14]=x3.z; xv[15]=x3.w;
        #pragma unroll
        for (int i = 0; i < 16; ++i) {
            acc.x += xv[i] * wds[i].x;
            acc.y += xv[i] * wds[i].y;
            acc.z += xv[i] * wds[i].z;
            acc.w += xv[i] * wds[i].w;
        }
        f32x4 accv;
        accv.x = acc.x; accv.y = acc.y; accv.z = acc.z; accv.w = acc.w;
        __builtin_nontemporal_store(accv, &out4[rowbase + q]);
    }
}

extern "C" void kernel_launch(void* const* d_in, const int* in_sizes, int n_in,
                              void* d_out, int out_size, void* d_ws, size_t ws_size,
                              hipStream_t stream) {
    const float* x      = (const float*)d_in[0];
    const float* w_diag = (const float*)d_in[1];
    const float* w_off  = (const float*)d_in[2];
    const float* b1     = (const float*)d_in[3];
    const int*   P      = (const int*)d_in[4];
    float* out    = (float*)d_out;
    float* s      = (float*)d_ws;          // 65536 floats
    float* off    = s + 65536;             // 65536 floats
    float* wd_t   = off + 65536;           // 65536 floats
    int*   c_of_n = (int*)(wd_t + 65536);  // 65536 ints

    k_sum_prep<<<B_ * C_ + 512, 256, 0, stream>>>(x, w_diag, P, s, wd_t, c_of_n);
    k_off<<<C_ * 4, 512, 0, stream>>>(w_off, s, b1, off);
    k_apply_seq<<<N_ / 64, 256, 0, stream>>>(x, c_of_n, wd_t, off, out);
}

// Round 7
// 214.501 us; speedup vs baseline: 1.3616x; 1.0290x over previous
//
#include <hip/hip_runtime.h>

#define B_    16
#define N_    65536
#define C_    256
#define DIN_  16
#define DOUT_ 16

typedef float f32x4 __attribute__((ext_vector_type(4)));

// workspace layout (floats):
//   s      [B_][DIN_][C_]    = 65536 floats  (s[b][i][k])  <- NEW layout
//   off    [B_][C_][DOUT_]   = 65536 floats  (includes /N and +b1)
//   wd_t   [C_][DIN_*DOUT_]  = 65536 floats  (wd_t[c][i*16+o])
//   c_of_n [N_]              = 65536 ints    (cluster id of source row n)

// ---------------------------------------------------------------------------
// K1: fused prep + cluster sums (gather form — R0-proven, ~34 µs).
//   blocks [0, 4096): gather-style cluster sum for (b, k) — no atomics.
//   blocks [4096, 4352): transpose w_diag[o][i][c] -> wd_t[c][i*16+o]
//   blocks [4352, 4608): c_of_n[P[j]] = j>>8
// Only change vs R6: final write targets s[b][i][k] layout.
// ---------------------------------------------------------------------------
__global__ __launch_bounds__(256) void k_sum_prep(
    const float* __restrict__ x, const float* __restrict__ w_diag,
    const int* __restrict__ P, float* __restrict__ s,
    float* __restrict__ wd_t, int* __restrict__ c_of_n)
{
    int bid = blockIdx.x;
    int t = threadIdx.x;
    if (bid >= B_ * C_) {
        int r = bid - B_ * C_;
        if (r < 256) {
            int o = r >> 4, i = r & 15;
            wd_t[t * 256 + i * 16 + o] = w_diag[r * C_ + t];  // coalesced read
        } else {
            int k = r - 256;
            c_of_n[P[k * 256 + t]] = k;
        }
        return;
    }
    int b = bid >> 8;
    int k = bid & (C_ - 1);
    int q  = t & 3;         // which float4 of the 16-float row
    int rg = t >> 2;        // 0..63 row group
    float4 acc = make_float4(0.f, 0.f, 0.f, 0.f);
    const int jbase = k << 8;
    #pragma unroll
    for (int m = 0; m < 4; ++m) {
        int n = P[jbase + rg + 64 * m];
        const float4* row =
            reinterpret_cast<const float4*>(x + ((size_t)(b * N_ + n)) * DIN_);
        float4 v = row[q];
        acc.x += v.x; acc.y += v.y; acc.z += v.z; acc.w += v.w;
    }
    // butterfly reduce over row-groups within the wave (bits 2..5 of lane id)
    #pragma unroll
    for (int mask = 4; mask <= 32; mask <<= 1) {
        acc.x += __shfl_xor(acc.x, mask, 64);
        acc.y += __shfl_xor(acc.y, mask, 64);
        acc.z += __shfl_xor(acc.z, mask, 64);
        acc.w += __shfl_xor(acc.w, mask, 64);
    }
    __shared__ float4 part[4][4];  // [wave][q]
    int lane = t & 63, wave = t >> 6;
    if (lane < 4) part[wave][lane] = acc;  // lane == q for lanes 0..3
    __syncthreads();
    if (t < 16) {
        int qq = t >> 2, comp = t & 3;
        float v = 0.f;
        #pragma unroll
        for (int w = 0; w < 4; ++w) {
            const float* p = reinterpret_cast<const float*>(&part[w][qq]);
            v += p[comp];
        }
        int i = qq * 4 + comp;
        s[(b * DIN_ + i) * C_ + k] = v;   // s[b][i][k]
    }
}

// ---------------------------------------------------------------------------
// K2 (barrier-free, LDS-free): off[b,c,o] = invN*sum_{i,k} w_off[o,i,c,k]*s[b,i,k] + b1[o]
// grid = 512 blocks: c = g&255, b-half = g>>8 (g and g+256 land on the SAME
//   CU at 2 blocks/CU -> duplicated w-read is an L1/L2 hit).
// 512 threads = 8 waves; wave wv owns o-pair o0 = 2*wv; lane kq owns k-quad.
// s addresses are IDENTICAL across the 8 waves (independent of o) -> L1
//   broadcast; all loads fully coalesced; zero synchronization; the compiler
//   pipelines the fully-unrolled 16x8 FMA body freely.
// Tail: fold-halving wave reduce (16 vals), lane<16 holds j = bitrev4(lane).
// ---------------------------------------------------------------------------
__global__ __launch_bounds__(512, 4) void k_off(
    const float* __restrict__ w_off, const float* __restrict__ s,
    const float* __restrict__ b1, float* __restrict__ off)
{
    const int g  = (int)blockIdx.x;
    const int c  = g & 255;
    const int b0 = (g >> 8) * 8;
    const int t  = threadIdx.x;       // 0..511
    const int kq = t & 63;
    const int wv = t >> 6;            // 0..7
    const int o0 = wv * 2;

    const float4* w4 = reinterpret_cast<const float4*>(w_off);
    const float4* s4 = reinterpret_cast<const float4*>(s);

    // fl4 index of w_off[o][i][c][4kq] = ((o*16+i)*256 + c)*64 + kq
    const int wb0 = ((o0 * 16) * 256 + c) * 64 + kq;        // o0, i=0
    const int wb1 = wb0 + 262144;                           // o0+1 (o-stride)
    // fl4 index of s[b][i][4kq] = (b*16 + i)*64 + kq
    const int sb  = (b0 * 16) * 64 + kq;

    float acc[16];   // acc[oo*8 + bb]
    #pragma unroll
    for (int z = 0; z < 16; ++z) acc[z] = 0.f;

    #pragma unroll
    for (int i = 0; i < DIN_; ++i) {
        float4 w0 = w4[wb0 + i * 16384];
        float4 w1 = w4[wb1 + i * 16384];
        #pragma unroll
        for (int bb = 0; bb < 8; ++bb) {
            float4 sv = s4[sb + (bb * 16 + i) * 64];
            acc[bb]     += w0.x * sv.x + w0.y * sv.y + w0.z * sv.z + w0.w * sv.w;
            acc[8 + bb] += w1.x * sv.x + w1.y * sv.y + w1.z * sv.z + w1.w * sv.w;
        }
    }

    // fold-halving reduce: 16 values x 64 lanes -> lane<16 holds bitrev4(lane)
#define FOLD(MASK, CNT)                                                        \
    {                                                                          \
        const bool hi_ = (kq & (MASK)) != 0;                                   \
        _Pragma("unroll")                                                      \
        for (int j = 0; j < (CNT); ++j) {                                      \
            float keep = hi_ ? acc[j + (CNT)] : acc[j];                        \
            float send = hi_ ? acc[j] : acc[j + (CNT)];                        \
            acc[j] = keep + __shfl_xor(send, (MASK), 64);                      \
        }                                                                      \
    }
    FOLD(1, 8) FOLD(2, 4) FOLD(4, 2) FOLD(8, 1)
#undef FOLD
    acc[0] += __shfl_xor(acc[0], 16, 64);
    acc[0] += __shfl_xor(acc[0], 32, 64);

    if (kq < 16) {
        int j  = ((kq & 1) << 3) | ((kq & 2) << 1) | ((kq & 4) >> 1) | ((kq & 8) >> 3);
        int oo = j >> 3;
        int bb = j & 7;
        int b  = b0 + bb;
        int o  = o0 + oo;
        off[((b << 8) + c) * DOUT_ + o] = acc[0] * (1.0f / (float)N_) + b1[o];
    }
}

// ---------------------------------------------------------------------------
// K3: sequential apply. Non-temporal out stores (out never re-read; keep
// x / w_off L3-resident). (unchanged)
// ---------------------------------------------------------------------------
__global__ __launch_bounds__(256) void k_apply_seq(
    const float* __restrict__ x, const int* __restrict__ c_of_n,
    const float* __restrict__ wd_t, const float* __restrict__ off,
    float* __restrict__ out)
{
    int t = threadIdx.x;
    int lr = t >> 2, q = t & 3;
    int n = blockIdx.x * 64 + lr;
    int c = c_of_n[n];

    const float4* wd4 = reinterpret_cast<const float4*>(wd_t);
    float4 wds[16];
    #pragma unroll
    for (int i = 0; i < 16; ++i) wds[i] = wd4[c * 64 + i * 4 + q];

    const float4* x4   = reinterpret_cast<const float4*>(x);
    const float4* off4 = reinterpret_cast<const float4*>(off);
    f32x4* out4        = reinterpret_cast<f32x4*>(out);

    #pragma unroll 2
    for (int b = 0; b < B_; ++b) {
        size_t rowbase = ((size_t)(b * N_ + n)) * 4;
        float4 x0 = x4[rowbase + 0];
        float4 x1 = x4[rowbase + 1];
        float4 x2 = x4[rowbase + 2];
        float4 x3 = x4[rowbase + 3];
        float4 acc = off4[((size_t)((b << 8) + c)) * 4 + q];
        float xv[16];
        xv[0]=x0.x; xv[1]=x0.y; xv[2]=x0.z; xv[3]=x0.w;
        xv[4]=x1.x; xv[5]=x1.y; xv[6]=x1.z; xv[7]=x1.w;
        xv[8]=x2.x; xv[9]=x2.y; xv[10]=x2.z; xv[11]=x2.w;
        xv[12]=x3.x; xv[13]=x3.y; xv[14]=x3.z; xv[15]=x3.w;
        #pragma unroll
        for (int i = 0; i < 16; ++i) {
            acc.x += xv[i] * wds[i].x;
            acc.y += xv[i] * wds[i].y;
            acc.z += xv[i] * wds[i].z;
            acc.w += xv[i] * wds[i].w;
        }
        f32x4 accv;
        accv.x = acc.x; accv.y = acc.y; accv.z = acc.z; accv.w = acc.w;
        __builtin_nontemporal_store(accv, &out4[rowbase + q]);
    }
}

extern "C" void kernel_launch(void* const* d_in, const int* in_sizes, int n_in,
                              void* d_out, int out_size, void* d_ws, size_t ws_size,
                              hipStream_t stream) {
    const float* x      = (const float*)d_in[0];
    const float* w_diag = (const float*)d_in[1];
    const float* w_off  = (const float*)d_in[2];
    const float* b1     = (const float*)d_in[3];
    const int*   P      = (const int*)d_in[4];
    float* out    = (float*)d_out;
    float* s      = (float*)d_ws;          // 65536 floats (s[b][i][k])
    float* off    = s + 65536;             // 65536 floats
    float* wd_t   = off + 65536;           // 65536 floats
    int*   c_of_n = (int*)(wd_t + 65536);  // 65536 ints

    k_sum_prep<<<B_ * C_ + 512, 256, 0, stream>>>(x, w_diag, P, s, wd_t, c_of_n);
    k_off<<<512, 512, 0, stream>>>(w_off, s, b1, off);
    k_apply_seq<<<N_ / 64, 256, 0, stream>>>(x, c_of_n, wd_t, off, out);
}

// Round 9
// 197.341 us; speedup vs baseline: 1.4800x; 1.0870x over previous
//
#include <hip/hip_runtime.h>

#define B_    16
#define N_    65536
#define C_    256
#define DIN_  16
#define DOUT_ 16

typedef float f32x4 __attribute__((ext_vector_type(4)));

// workspace layout (floats):
//   s      [B_][DIN_][C_]    = 65536 floats  (s[b][i][k])
//   off    [B_][C_][DOUT_]   = 65536 floats  (b1-prefilled; k_off atomically
//                                             accumulates invN-scaled partials)
//   wd_t   [C_][DIN_*DOUT_]  = 65536 floats  (wd_t[c][i*16+o])
//   c_of_n [N_]              = 65536 ints    (cluster id of source row n)

// ---------------------------------------------------------------------------
// K1: fused prep + cluster sums (gather form — R0-proven, ~34 µs).
//   blocks [0, 4096): gather-style cluster sum for (b, k) — no atomics.
//   blocks [4096, 4352): transpose w_diag[o][i][c] -> wd_t[c][i*16+o]
//   blocks [4352, 4608): c_of_n[P[j]] = j>>8
//   blocks [4608, 4864): off[b][c][o] = b1[o]   (256 blocks — FULL 65536
//                        coverage; R8 bug was 64 blocks = b<4 only)
// ---------------------------------------------------------------------------
__global__ __launch_bounds__(256) void k_sum_prep(
    const float* __restrict__ x, const float* __restrict__ w_diag,
    const int* __restrict__ P, const float* __restrict__ b1,
    float* __restrict__ s, float* __restrict__ wd_t,
    int* __restrict__ c_of_n, float* __restrict__ off)
{
    int bid = blockIdx.x;
    int t = threadIdx.x;
    if (bid >= B_ * C_) {
        int r = bid - B_ * C_;
        if (r < 256) {
            int o = r >> 4, i = r & 15;
            wd_t[t * 256 + i * 16 + o] = w_diag[r * C_ + t];  // coalesced read
        } else if (r < 512) {
            int k = r - 256;
            c_of_n[P[k * 256 + t]] = k;
        } else {
            int m = (r - 512) * 256 + t;   // r-512 in [0,256) -> m in [0,65536)
            off[m] = b1[m & 15];
        }
        return;
    }
    int b = bid >> 8;
    int k = bid & (C_ - 1);
    int q  = t & 3;         // which float4 of the 16-float row
    int rg = t >> 2;        // 0..63 row group
    float4 acc = make_float4(0.f, 0.f, 0.f, 0.f);
    const int jbase = k << 8;
    #pragma unroll
    for (int m = 0; m < 4; ++m) {
        int n = P[jbase + rg + 64 * m];
        const float4* row =
            reinterpret_cast<const float4*>(x + ((size_t)(b * N_ + n)) * DIN_);
        float4 v = row[q];
        acc.x += v.x; acc.y += v.y; acc.z += v.z; acc.w += v.w;
    }
    // butterfly reduce over row-groups within the wave (bits 2..5 of lane id)
    #pragma unroll
    for (int mask = 4; mask <= 32; mask <<= 1) {
        acc.x += __shfl_xor(acc.x, mask, 64);
        acc.y += __shfl_xor(acc.y, mask, 64);
        acc.z += __shfl_xor(acc.z, mask, 64);
        acc.w += __shfl_xor(acc.w, mask, 64);
    }
    __shared__ float4 part[4][4];  // [wave][q]
    int lane = t & 63, wave = t >> 6;
    if (lane < 4) part[wave][lane] = acc;  // lane == q for lanes 0..3
    __syncthreads();
    if (t < 16) {
        int qq = t >> 2, comp = t & 3;
        float v = 0.f;
        #pragma unroll
        for (int w = 0; w < 4; ++w) {
            const float* p = reinterpret_cast<const float*>(&part[w][qq]);
            v += p[comp];
        }
        int i = qq * 4 + comp;
        s[(b * DIN_ + i) * C_ + k] = v;   // s[b][i][k]
    }
}

// ---------------------------------------------------------------------------
// K2 (MLP-forced, i-split): partial over i-quarter, atomic-accumulated.
//   off[b,c,o] += invN * sum_{i in quarter, k} w_off[o,i,c,k] * s[b,i,k]
// grid = 4096 blocks: c = g&255, o-quad og = (g>>8)&3, i-quarter iq = g>>10.
// 256 threads = 4 waves; wave bq owns b-quad; lane kq owns k-quad.
// ALL 32 float4 loads (4i x (4 w + 4 s)) are issued into named buffers, then
// sched_barrier(0) forces them live across the FMA block -> ~160 VGPR,
// 32 outstanding loads/wave. 16384 independent waves, no LDS, no barriers.
// Tail: fold-halving wave reduce; lane<16 atomicAdd into b1-prefilled off.
// ---------------------------------------------------------------------------
__global__ __launch_bounds__(256) void k_off(
    const float* __restrict__ w_off, const float* __restrict__ s,
    float* __restrict__ off)
{
    const int g  = (int)blockIdx.x;   // 0..4095
    const int c  = g & 255;
    const int o0 = ((g >> 8) & 3) * 4;
    const int i0 = (g >> 10) * 4;
    const int t  = threadIdx.x;
    const int kq = t & 63;
    const int b0 = (t >> 6) * 4;      // wave id -> b-quad

    const float4* w4 = reinterpret_cast<const float4*>(w_off);
    const float4* s4 = reinterpret_cast<const float4*>(s);

    // issue ALL 32 loads first (independent; max indices < 2^22, int-safe)
    float4 wv[4][4];   // [ii][oo]
    float4 sv[4][4];   // [ii][bb]
    #pragma unroll
    for (int ii = 0; ii < 4; ++ii) {
        const int i = i0 + ii;
        #pragma unroll
        for (int oo = 0; oo < 4; ++oo)
            wv[ii][oo] = w4[(((o0 + oo) * 16 + i) * 256 + c) * 64 + kq];
        #pragma unroll
        for (int bb = 0; bb < 4; ++bb)
            sv[ii][bb] = s4[((b0 + bb) * 16 + i) * 64 + kq];
    }
    __builtin_amdgcn_sched_barrier(0);   // no FMA may be hoisted above; all
                                         // 32 loads stay in flight together

    float acc[16];   // acc[oo*4 + bb]
    #pragma unroll
    for (int z = 0; z < 16; ++z) acc[z] = 0.f;

    #pragma unroll
    for (int ii = 0; ii < 4; ++ii) {
        #pragma unroll
        for (int oo = 0; oo < 4; ++oo) {
            #pragma unroll
            for (int bb = 0; bb < 4; ++bb) {
                acc[oo * 4 + bb] += wv[ii][oo].x * sv[ii][bb].x
                                  + wv[ii][oo].y * sv[ii][bb].y
                                  + wv[ii][oo].z * sv[ii][bb].z
                                  + wv[ii][oo].w * sv[ii][bb].w;
            }
        }
    }

    // fold-halving reduce: 16 values x 64 lanes -> lane<16 holds bitrev4(lane)
#define FOLD(MASK, CNT)                                                        \
    {                                                                          \
        const bool hi_ = (kq & (MASK)) != 0;                                   \
        _Pragma("unroll")                                                      \
        for (int j = 0; j < (CNT); ++j) {                                      \
            float keep = hi_ ? acc[j + (CNT)] : acc[j];                        \
            float send = hi_ ? acc[j] : acc[j + (CNT)];                        \
            acc[j] = keep + __shfl_xor(send, (MASK), 64);                      \
        }                                                                      \
    }
    FOLD(1, 8) FOLD(2, 4) FOLD(4, 2) FOLD(8, 1)
#undef FOLD
    acc[0] += __shfl_xor(acc[0], 16, 64);
    acc[0] += __shfl_xor(acc[0], 32, 64);

    if (kq < 16) {
        int j  = ((kq & 1) << 3) | ((kq & 2) << 1) | ((kq & 4) >> 1) | ((kq & 8) >> 3);
        int oo = j >> 2;
        int bb = j & 3;
        int b  = b0 + bb;
        int o  = o0 + oo;
        atomicAdd(&off[((b << 8) + c) * DOUT_ + o], acc[0] * (1.0f / (float)N_));
    }
}

// ---------------------------------------------------------------------------
// K3: sequential apply. Non-temporal out stores (out never re-read; keep
// x / w_off L3-resident). (unchanged)
// ---------------------------------------------------------------------------
__global__ __launch_bounds__(256) void k_apply_seq(
    const float* __restrict__ x, const int* __restrict__ c_of_n,
    const float* __restrict__ wd_t, const float* __restrict__ off,
    float* __restrict__ out)
{
    int t = threadIdx.x;
    int lr = t >> 2, q = t & 3;
    int n = blockIdx.x * 64 + lr;
    int c = c_of_n[n];

    const float4* wd4 = reinterpret_cast<const float4*>(wd_t);
    float4 wds[16];
    #pragma unroll
    for (int i = 0; i < 16; ++i) wds[i] = wd4[c * 64 + i * 4 + q];

    const float4* x4   = reinterpret_cast<const float4*>(x);
    const float4* off4 = reinterpret_cast<const float4*>(off);
    f32x4* out4        = reinterpret_cast<f32x4*>(out);

    #pragma unroll 2
    for (int b = 0; b < B_; ++b) {
        size_t rowbase = ((size_t)(b * N_ + n)) * 4;
        float4 x0 = x4[rowbase + 0];
        float4 x1 = x4[rowbase + 1];
        float4 x2 = x4[rowbase + 2];
        float4 x3 = x4[rowbase + 3];
        float4 acc = off4[((size_t)((b << 8) + c)) * 4 + q];
        float xv[16];
        xv[0]=x0.x; xv[1]=x0.y; xv[2]=x0.z; xv[3]=x0.w;
        xv[4]=x1.x; xv[5]=x1.y; xv[6]=x1.z; xv[7]=x1.w;
        xv[8]=x2.x; xv[9]=x2.y; xv[10]=x2.z; xv[11]=x2.w;
        xv[12]=x3.x; xv[13]=x3.y; xv[14]=x3.z; xv[15]=x3.w;
        #pragma unroll
        for (int i = 0; i < 16; ++i) {
            acc.x += xv[i] * wds[i].x;
            acc.y += xv[i] * wds[i].y;
            acc.z += xv[i] * wds[i].z;
            acc.w += xv[i] * wds[i].w;
        }
        f32x4 accv;
        accv.x = acc.x; accv.y = acc.y; accv.z = acc.z; accv.w = acc.w;
        __builtin_nontemporal_store(accv, &out4[rowbase + q]);
    }
}

extern "C" void kernel_launch(void* const* d_in, const int* in_sizes, int n_in,
                              void* d_out, int out_size, void* d_ws, size_t ws_size,
                              hipStream_t stream) {
    const float* x      = (const float*)d_in[0];
    const float* w_diag = (const float*)d_in[1];
    const float* w_off  = (const float*)d_in[2];
    const float* b1     = (const float*)d_in[3];
    const int*   P      = (const int*)d_in[4];
    float* out    = (float*)d_out;
    float* s      = (float*)d_ws;          // 65536 floats (s[b][i][k])
    float* off    = s + 65536;             // 65536 floats
    float* wd_t   = off + 65536;           // 65536 floats
    int*   c_of_n = (int*)(wd_t + 65536);  // 65536 ints

    k_sum_prep<<<B_ * C_ + 768, 256, 0, stream>>>(x, w_diag, P, b1,
                                                  s, wd_t, c_of_n, off);
    k_off<<<4096, 256, 0, stream>>>(w_off, s, off);
    k_apply_seq<<<N_ / 64, 256, 0, stream>>>(x, c_of_n, wd_t, off, out);
}